// Round 15
// baseline (693.643 us; speedup 1.0000x reference)
//
#include <hip/hip_runtime.h>
#include <hip/hip_bf16.h>

#define NN 8192
#define NE 262144
#define DN 128
#define DE 10
#define DM 64
#define HL 256
#define DA 512

#define CS 64   // LSTM time-chunk size per WG
#define KW 32   // warm-up steps: empirically exact at current error scale

typedef __attribute__((ext_vector_type(2))) _Float16 h2_t;
typedef __attribute__((ext_vector_type(8))) short short8;
typedef __attribute__((ext_vector_type(4))) float f32x4;
typedef __attribute__((ext_vector_type(8))) int int32x8;

__device__ __forceinline__ float fast_rcp(float x) {
#if __has_builtin(__builtin_amdgcn_rcpf)
  return __builtin_amdgcn_rcpf(x);
#else
  return 1.0f / x;
#endif
}
__device__ __forceinline__ float sigf(float x) {
  return fast_rcp(1.0f + __expf(-x));
}
__device__ __forceinline__ float tanh_fast(float x) {
  return 2.0f * fast_rcp(1.0f + __expf(-2.0f * x)) - 1.0f;
}
__device__ __forceinline__ float fdot2f(h2_t a, h2_t b, float c) {
#if __has_builtin(__builtin_amdgcn_fdot2)
  return __builtin_amdgcn_fdot2(a, b, c, false);
#else
  return c + (float)a.x * (float)b.x + (float)a.y * (float)b.y;
#endif
}
__device__ __forceinline__ h2_t bch2(unsigned int u) {
  return __builtin_bit_cast(h2_t, u);
}
__device__ __forceinline__ unsigned short f2bf(float v) {
  return __builtin_bit_cast(unsigned short, __float2bfloat16(v));
}

// Manual f32 -> OCP e4m3fn with RNE.
__device__ __forceinline__ unsigned char f2e4m3(float f) {
  unsigned int u = __builtin_bit_cast(unsigned int, f);
  unsigned int sign = (u >> 24) & 0x80u;
  unsigned int au = u & 0x7FFFFFFFu;
  float a = __builtin_bit_cast(float, au);
  if (a >= 464.0f) return (unsigned char)(sign | 0x7Eu);
  int e = (int)((au >> 23) & 0xFFu) - 127;
  if (e >= -6) {
    unsigned int man = au & 0x7FFFFFu;
    unsigned int m = man >> 20;
    unsigned int rest = man & 0xFFFFFu;
    m += (rest > 0x80000u) || ((rest == 0x80000u) && (m & 1u));
    unsigned int ee = (unsigned)(e + 7);
    if (m >= 8u) { m -= 8u; ee += 1u; }
    if (ee > 15u || (ee == 15u && m > 6u)) return (unsigned char)(sign | 0x7Eu);
    return (unsigned char)(sign | (ee << 3) | m);
  }
  int q = (int)rintf(a * 512.0f);
  if (q >= 8) return (unsigned char)(sign | 0x08u);
  return (unsigned char)(sign | (unsigned)q);
}

__device__ __forceinline__ int32x8 pack8(uint4 a, uint4 b) {
  int32x8 r;
  r[0] = (int)a.x; r[1] = (int)a.y; r[2] = (int)a.z; r[3] = (int)a.w;
  r[4] = (int)b.x; r[5] = (int)b.y; r[6] = (int)b.z; r[7] = (int)b.w;
  return r;
}

// ---------------- CSR build ----------------
__global__ void k_csr_hist(const int* __restrict__ ei, unsigned int* __restrict__ deg) {
  int e = blockIdx.x * 256 + threadIdx.x;
  if (e < NE) atomicAdd(&deg[ei[NE + e]], 1u);
}

__global__ __launch_bounds__(256) void k_csr_scan(
    const unsigned int* __restrict__ deg, unsigned int* __restrict__ rowptr,
    unsigned int* __restrict__ cursor) {
  __shared__ unsigned int tot[256];
  int t = threadIdx.x;
  unsigned int local[32];
  unsigned int s = 0;
  for (int i = 0; i < 32; ++i) {
    local[i] = s;
    s += deg[t * 32 + i];
  }
  tot[t] = s;
  __syncthreads();
  for (int d = 1; d < 256; d <<= 1) {
    unsigned int v = (t >= d) ? tot[t - d] : 0u;
    __syncthreads();
    tot[t] += v;
    __syncthreads();
  }
  unsigned int base = (t == 0) ? 0u : tot[t - 1];
  for (int i = 0; i < 32; ++i) {
    unsigned int r = base + local[i];
    rowptr[t * 32 + i] = r;
    cursor[t * 32 + i] = r;
  }
  if (t == 255) rowptr[NN] = tot[255];
}

// Fill stores BOTH the edge id (for ea) and the source node (pre-gathered,
// removes a dependent load hop in k_aggr).
__global__ void k_csr_fill(const int* __restrict__ ei, unsigned int* __restrict__ cursor,
                           int* __restrict__ eidx, int* __restrict__ esrc) {
  int e = blockIdx.x * 256 + threadIdx.x;
  if (e < NE) {
    int d = ei[NE + e];
    unsigned int p = atomicAdd(&cursor[d], 1u);
    eidx[p] = e;
    esrc[p] = ei[e];
  }
}

// Gather-aggregate: aggr[n] = W @ (sum_e concat(x[src],ea)) + deg*b.
__global__ __launch_bounds__(256) void k_aggr(
    const float* __restrict__ x, const float* __restrict__ ea,
    const int* __restrict__ eidx, const int* __restrict__ esrc,
    const unsigned int* __restrict__ rowptr, const float* __restrict__ mw,
    const float* __restrict__ mb, float* __restrict__ aggr) {
  __shared__ float wT[DN + DE][DM];
  __shared__ float feat[4][DN + DE + 2];
  for (int i = threadIdx.x; i < (DN + DE) * DM; i += 256) {
    int k = i >> 6, o = i & 63;
    wT[k][o] = mw[o * (DN + DE) + k];
  }
  __syncthreads();
  int wv = threadIdx.x >> 6;
  int l = threadIdx.x & 63;
  int n = blockIdx.x * 4 + wv;
  unsigned int e0 = rowptr[n], e1 = rowptr[n + 1];
  float s0 = 0.f, s1 = 0.f, se = 0.f;
  for (unsigned int i = e0; i < e1; ++i) {
    int src = esrc[i];
    int e = eidx[i];
    const float* xr = x + (size_t)src * DN;
    s0 += xr[l];
    s1 += xr[64 + l];
    if (l < DE) se += ea[(size_t)e * DE + l];
  }
  feat[wv][l] = s0;
  feat[wv][64 + l] = s1;
  if (l < DE) feat[wv][128 + l] = se;
  __syncthreads();
  float degc = (float)(e1 - e0);
  float acc = mb[l] * degc;
#pragma unroll 2
  for (int k = 0; k < DN + DE; ++k) acc += feat[wv][k] * wT[k][l];
  aggr[(size_t)n * DM + l] = acc;
}

// Node update; emits h directly as f16 (sole consumer is the f16 gate MFMA).
__global__ void k_update(const float* __restrict__ x, const float* __restrict__ aggr,
                         const float* __restrict__ uw, const float* __restrict__ ub,
                         _Float16* __restrict__ h16) {
  __shared__ float l[16][DN + DM];
  int r0 = blockIdx.x * 16;
  for (int i = threadIdx.x; i < 16 * (DN + DM); i += 128) {
    int r = i / (DN + DM), k = i % (DN + DM);
    l[r][k] = (k < DN) ? x[(size_t)(r0 + r) * DN + k]
                       : aggr[(size_t)(r0 + r) * DM + (k - DN)];
  }
  __syncthreads();
  int o = threadIdx.x;
  float b = ub[o];
  float acc[16];
#pragma unroll
  for (int r = 0; r < 16; ++r) acc[r] = b;
  const float* wr = uw + (size_t)o * (DN + DM);
  for (int k = 0; k < DN + DM; ++k) {
    float wv = wr[k];
#pragma unroll
    for (int r = 0; r < 16; ++r) acc[r] += wv * l[r][k];
  }
#pragma unroll
  for (int r = 0; r < 16; ++r) h16[(size_t)(r0 + r) * DN + o] = (_Float16)acc[r];
}

// Gate GEMM v3: f16 MFMA, k_inproj pattern.
__global__ __launch_bounds__(256) void k_gates3(
    const _Float16* __restrict__ h16,
    const _Float16* __restrict__ wif16, const _Float16* __restrict__ wir16,
    const float* __restrict__ bif, const float* __restrict__ bhf,
    const float* __restrict__ bir, const float* __restrict__ bhr,
    float* __restrict__ gf, float* __restrict__ gr) {
  int rt = blockIdx.x >> 3;
  int cg = blockIdx.x & 7;
  int w = threadIdx.x >> 6;
  int lane = threadIdx.x & 63;
  int r0 = rt * 16;
  int rA = lane & 15;
  int kg = lane >> 4;
  int rev = cg >> 2;
  int colbase = (cg & 3) * 256 + w * 64;
  const _Float16* wb = rev ? wir16 : wif16;
  const float* b1 = rev ? bir : bif;
  const float* b2 = rev ? bhr : bhf;

  short8 a[4];
#pragma unroll
  for (int kk = 0; kk < 4; ++kk)
    a[kk] = *(const short8*)(h16 + (size_t)(r0 + rA) * DN + kk * 32 + kg * 8);

  for (int ct = 0; ct < 4; ++ct) {
    int col0 = colbase + ct * 16;
    f32x4 acc = {0.f, 0.f, 0.f, 0.f};
#pragma unroll
    for (int kk = 0; kk < 4; ++kk) {
      short8 b = *(const short8*)(wb + (size_t)(col0 + rA) * DN + kk * 32 + kg * 8);
      acc = __builtin_amdgcn_mfma_f32_16x16x32_f16(a[kk], b, acc, 0, 0, 0);
    }
    int col = col0 + rA;
    float bsum = b1[col] + b2[col];
#pragma unroll
    for (int i = 0; i < 4; ++i) {
      int row = r0 + kg * 4 + i;
      float v = acc[i] + bsum;
      if (!rev) gf[(size_t)row * 1024 + col] = v;
      else      gr[(size_t)(NN - 1 - row) * 1024 + col] = v;
    }
  }
}

// Fused weight conversions: w_hh (f,r) -> f16, w_ih (f,r) -> f16, ipw[q,k] -> bf16.
__global__ void k_prep(const float* __restrict__ whhf, const float* __restrict__ whhr,
                       const float* __restrict__ wihf, const float* __restrict__ wihr,
                       const float* __restrict__ ipw,
                       _Float16* __restrict__ wpf, _Float16* __restrict__ wpr,
                       _Float16* __restrict__ wif16, _Float16* __restrict__ wir16,
                       unsigned short* __restrict__ wbf) {
  int i = blockIdx.x * 256 + threadIdx.x;
  if (i < 1024 * HL) {
    wpf[i] = (_Float16)whhf[i];
    wpr[i] = (_Float16)whhr[i];
  } else if (i < 1024 * HL + 1024 * DN) {
    int j = i - 1024 * HL;
    wif16[j] = (_Float16)wihf[j];
    wir16[j] = (_Float16)wihr[j];
  } else {
    int j = i - (1024 * HL + 1024 * DN);
    wbf[j] = f2bf(ipw[j]);
  }
}

// Fused epilogue-algebra prep: effw (LDS), then wveff + scal[0,1].
__global__ __launch_bounds__(512) void k_eff(
    const float* __restrict__ opw, const float* __restrict__ fcw,
    const float* __restrict__ fcb, const float* __restrict__ opb,
    const float* __restrict__ ipb, const float* __restrict__ ipw,
    float* __restrict__ wveff, float* __restrict__ scal) {
  __shared__ float eff[512];
  __shared__ float red[512];
  int t = threadIdx.x;
  float s = 0.f;
  for (int d = 0; d < DA; ++d) s += fcw[d] * opw[(size_t)d * DA + t];
  eff[t] = s;
  __syncthreads();
  float wv = 0.f;
  for (int k = 0; k < DA; ++k) wv += eff[k] * ipw[(size_t)(2 * DA + k) * DA + t];
  wveff[t] = wv;
  red[t] = fcw[t] * opb[t];
  __syncthreads();
  for (int s2 = 256; s2 > 0; s2 >>= 1) {
    if (t < s2) red[t] += red[t + s2];
    __syncthreads();
  }
  if (t == 0) scal[0] = red[0] + fcb[0];
  __syncthreads();
  red[t] = ipb[2 * DA + t] * eff[t];
  __syncthreads();
  for (int s2 = 256; s2 > 0; s2 >>= 1) {
    if (t < s2) red[t] += red[t + s2];
    __syncthreads();
  }
  if (t == 0) scal[1] = red[0];
}

// Time-chunked BiLSTM v5: K-QUARTER split. 1024 threads; kh = tid>>8 owns
// K-range [kh*64, kh*64+64); j = tid&255 is the hidden index. i/f/o quarter
// rows = 96 h2 VGPRs (fits the 128-VGPR budget at 4 waves/SIMD -> no AGPR
// operand shuffling on the fdot2s). g-gate quarter in rotation-swizzled LDS.
// Same two-barrier v4 skeleton; part[3][256] combine; kh0 does the update.
__global__ __launch_bounds__(1024, 1) void k_lstm5(
    const _Float16* __restrict__ wp_f, const _Float16* __restrict__ wp_r,
    const float* __restrict__ gf, const float* __restrict__ gr,
    float* __restrict__ lstm_out, unsigned short* __restrict__ lstm_bf) {
  int dir = blockIdx.x & 1;
  int chunk = blockIdx.x >> 1;
  int tid = threadIdx.x;
  int kh = tid >> 8;
  int j = tid & 255;
  const _Float16* wp = dir ? wp_r : wp_f;
  const float* gates = dir ? gr : gf;

  __shared__ uint4 gw4[256 * 32];      // 128 KB g-gate rows (full K), swizzled
  __shared__ unsigned int hsu[2][128]; // h as f16 pairs, double-buffered
  __shared__ float4 part[3 * 256];     // partials from kh=1..3

  h2_t wi[32], wf2[32], wo[32];
  {
    const uint4* ri = (const uint4*)(wp + (size_t)j * HL + kh * 64);
    const uint4* rf = (const uint4*)(wp + (size_t)(256 + j) * HL + kh * 64);
    const uint4* ro = (const uint4*)(wp + (size_t)(768 + j) * HL + kh * 64);
#pragma unroll
    for (int s = 0; s < 8; ++s) {
      uint4 a = ri[s], b = rf[s], c = ro[s];
      wi[4 * s + 0] = bch2(a.x); wi[4 * s + 1] = bch2(a.y);
      wi[4 * s + 2] = bch2(a.z); wi[4 * s + 3] = bch2(a.w);
      wf2[4 * s + 0] = bch2(b.x); wf2[4 * s + 1] = bch2(b.y);
      wf2[4 * s + 2] = bch2(b.z); wf2[4 * s + 3] = bch2(b.w);
      wo[4 * s + 0] = bch2(c.x); wo[4 * s + 1] = bch2(c.y);
      wo[4 * s + 2] = bch2(c.z); wo[4 * s + 3] = bch2(c.w);
    }
  }
  {
    const uint4* rg = (const uint4*)(wp + (size_t)(512 + j) * HL + kh * 64);
#pragma unroll
    for (int s = 0; s < 8; ++s)
      gw4[j * 32 + ((kh * 8 + s + j) & 31)] = rg[s];
  }
  if (tid < 128) { hsu[0][tid] = 0u; hsu[1][tid] = 0u; }
  __syncthreads();

  int outstart = chunk * CS;
  int t0 = outstart - KW;
  if (t0 < 0) t0 = 0;
  int tend = outstart + CS;
  float c = 0.f;
  int cur = 0;
  int gro = kh * 8 + j;

  for (int t = t0; t < tend; ++t) {
    float gi0 = 0.f, gff0 = 0.f, gg0 = 0.f, go0 = 0.f;
    if (kh == 0) {
      const float* gp = gates + (size_t)t * 1024 + j;
      gi0 = gp[0]; gff0 = gp[256]; gg0 = gp[512]; go0 = gp[768];
    }
    float di = 0.f, df = 0.f, dg = 0.f, do_ = 0.f;
    const uint4* hb = (const uint4*)&hsu[cur][kh * 32];
#pragma unroll
    for (int s = 0; s < 8; ++s) {
      uint4 hq = hb[s];
      uint4 gq = gw4[j * 32 + ((gro + s) & 31)];
      di = fdot2f(wi[4 * s + 0], bch2(hq.x), di);
      di = fdot2f(wi[4 * s + 1], bch2(hq.y), di);
      di = fdot2f(wi[4 * s + 2], bch2(hq.z), di);
      di = fdot2f(wi[4 * s + 3], bch2(hq.w), di);
      df = fdot2f(wf2[4 * s + 0], bch2(hq.x), df);
      df = fdot2f(wf2[4 * s + 1], bch2(hq.y), df);
      df = fdot2f(wf2[4 * s + 2], bch2(hq.z), df);
      df = fdot2f(wf2[4 * s + 3], bch2(hq.w), df);
      dg = fdot2f(bch2(gq.x), bch2(hq.x), dg);
      dg = fdot2f(bch2(gq.y), bch2(hq.y), dg);
      dg = fdot2f(bch2(gq.z), bch2(hq.z), dg);
      dg = fdot2f(bch2(gq.w), bch2(hq.w), dg);
      do_ = fdot2f(wo[4 * s + 0], bch2(hq.x), do_);
      do_ = fdot2f(wo[4 * s + 1], bch2(hq.y), do_);
      do_ = fdot2f(wo[4 * s + 2], bch2(hq.z), do_);
      do_ = fdot2f(wo[4 * s + 3], bch2(hq.w), do_);
    }
    if (kh != 0) part[(kh - 1) * 256 + j] = (float4){di, df, dg, do_};
    __syncthreads();
    if (kh == 0) {
      float4 p1 = part[j];
      float4 p2 = part[256 + j];
      float4 p3 = part[512 + j];
      float i_ = sigf(gi0 + di + p1.x + p2.x + p3.x);
      float f_ = sigf(gff0 + df + p1.y + p2.y + p3.y);
      float g_ = tanh_fast(gg0 + dg + p1.z + p2.z + p3.z);
      float o_ = sigf(go0 + do_ + p1.w + p2.w + p3.w);
      c = f_ * c + i_ * g_;
      float hval = o_ * tanh_fast(c);
      if (t >= outstart) {
        size_t n = dir ? (size_t)(NN - 1 - t) : (size_t)t;
        lstm_out[n * DA + dir * HL + j] = hval;
        lstm_bf[n * DA + dir * HL + j] = f2bf(hval);
      }
      ((_Float16*)hsu[cur ^ 1])[j] = (_Float16)hval;
    }
    __syncthreads();
    cur ^= 1;
  }
}

__global__ void k_veff(const float* __restrict__ lstm, const float* __restrict__ wveff,
                       const float* __restrict__ scal, float* __restrict__ veff) {
  int row = blockIdx.x * 4 + (threadIdx.x >> 6);
  int lane = threadIdx.x & 63;
  const float4* a = (const float4*)(lstm + (size_t)row * DA + lane * 8);
  const float4* w = (const float4*)(wveff + lane * 8);
  float4 x0 = a[0], x1 = a[1], w0 = w[0], w1 = w[1];
  float s = x0.x * w0.x + x0.y * w0.y + x0.z * w0.z + x0.w * w0.w +
            x1.x * w1.x + x1.y * w1.y + x1.z * w1.z + x1.w * w1.w;
#pragma unroll
  for (int off = 1; off < 64; off <<= 1) s += __shfl_xor(s, off);
  if (lane == 0) veff[row] = s + scal[1];
}

// in_proj q,k via bf16 MFMA; outputs fp8 e4m3 (unscaled; 1/sqrt(512) applied
// post-MFMA in the attn passes).
__global__ void k_inproj(const unsigned short* __restrict__ lstm_bf,
                         const unsigned short* __restrict__ w_bf,
                         const float* __restrict__ ipb,
                         unsigned char* __restrict__ qf8,
                         unsigned char* __restrict__ kf8) {
  int rt = blockIdx.x >> 2;
  int cg = blockIdx.x & 3;
  int w = threadIdx.x >> 6;
  int lane = threadIdx.x & 63;
  int r0 = rt * 16;
  int rA = lane & 15;
  int kg = lane >> 4;
  short8 a[16];
#pragma unroll
  for (int kk = 0; kk < 16; ++kk)
    a[kk] = *(const short8*)(lstm_bf + (size_t)(r0 + rA) * DA + kk * 32 + kg * 8);
  for (int ct = 0; ct < 4; ++ct) {
    int col0 = cg * 256 + w * 64 + ct * 16;
    f32x4 acc = {0.f, 0.f, 0.f, 0.f};
#pragma unroll
    for (int kk = 0; kk < 16; ++kk) {
      short8 b = *(const short8*)(w_bf + (size_t)(col0 + rA) * DA + kk * 32 + kg * 8);
      acc = __builtin_amdgcn_mfma_f32_16x16x32_bf16(a[kk], b, acc, 0, 0, 0);
    }
    int col = col0 + rA;
    float bv = ipb[col];
#pragma unroll
    for (int i = 0; i < 4; ++i) {
      int rowo = r0 + kg * 4 + i;
      float v = acc[i] + bv;
      if (col < DA)
        qf8[(size_t)rowo * DA + col] = f2e4m3(v);
      else
        kf8[(size_t)rowo * DA + (col - DA)] = f2e4m3(v);
    }
  }
}

// ---- fp8 QK^T passes, operand-swapped (lane's 4 acc = 4 consecutive S-cols
// of one row): float4 stores, vectorized veff loads, 2-shfl reduction.

__global__ __launch_bounds__(256, 2) void k_zsum3(
    const unsigned char* __restrict__ qf8, const unsigned char* __restrict__ kf8,
    const float* __restrict__ veff,
    float* __restrict__ zpart, float* __restrict__ fpart) {
  int rb = blockIdx.x >> 4;
  int cs = blockIdx.x & 15;
  int w = threadIdx.x >> 6;
  int lane = threadIdx.x & 63;
  int rA = lane & 15, kg = lane >> 4;
  int rowbase = rb * 256 + w * 64;
  int cbase = cs * 512;
  const float rs = 0.04419417382415922f;

  int32x8 a8[4][4];  // Q rows (B-operand after swap)
#pragma unroll
  for (int rt = 0; rt < 4; ++rt)
#pragma unroll
    for (int ki = 0; ki < 4; ++ki) {
      const uint4* p = (const uint4*)(qf8 + (size_t)(rowbase + rt * 16 + rA) * DA + ki * 128 + kg * 32);
      a8[rt][ki] = pack8(p[0], p[1]);
    }
  float zs[4], fs[4];
#pragma unroll
  for (int rt = 0; rt < 4; ++rt) { zs[rt] = 0.f; fs[rt] = 0.f; }

  for (int ct = 0; ct < 32; ++ct) {
    int col0 = cbase + ct * 16;
    int32x8 b8[4];  // K cols (A-operand after swap)
#pragma unroll
    for (int ki = 0; ki < 4; ++ki) {
      const uint4* p = (const uint4*)(kf8 + (size_t)(col0 + rA) * DA + ki * 128 + kg * 32);
      b8[ki] = pack8(p[0], p[1]);
    }
    float4 vv4 = *(const float4*)&veff[col0 + kg * 4];
#pragma unroll
    for (int rt = 0; rt < 4; ++rt) {
      f32x4 acc = {0.f, 0.f, 0.f, 0.f};
#pragma unroll
      for (int ki = 0; ki < 4; ++ki)
        acc = __builtin_amdgcn_mfma_scale_f32_16x16x128_f8f6f4(
            b8[ki], a8[rt][ki], acc, 0, 0, 0, 127, 0, 127);
      float e0 = __expf(fminf(acc[0] * rs, 60.f));
      float e1 = __expf(fminf(acc[1] * rs, 60.f));
      float e2 = __expf(fminf(acc[2] * rs, 60.f));
      float e3 = __expf(fminf(acc[3] * rs, 60.f));
      zs[rt] += (e0 + e1) + (e2 + e3);
      fs[rt] += (e0 * vv4.x + e1 * vv4.y) + (e2 * vv4.z + e3 * vv4.w);
    }
  }
#pragma unroll
  for (int rt = 0; rt < 4; ++rt) {
    zs[rt] += __shfl_xor(zs[rt], 16);
    zs[rt] += __shfl_xor(zs[rt], 32);
    fs[rt] += __shfl_xor(fs[rt], 16);
    fs[rt] += __shfl_xor(fs[rt], 32);
  }
  if (lane < 16) {
#pragma unroll
    for (int rt = 0; rt < 4; ++rt) {
      int row = rowbase + rt * 16 + rA;
      zpart[(size_t)cs * NN + row] = zs[rt];
      fpart[(size_t)cs * NN + row] = fs[rt];
    }
  }
}

__global__ void k_zred(const float* __restrict__ zpart, const float* __restrict__ fpart,
                       const float* __restrict__ scal, float* __restrict__ invZa,
                       float* __restrict__ out) {
  int row = blockIdx.x * 256 + threadIdx.x;
  float Z = 0.f, F = 0.f;
#pragma unroll
  for (int p = 0; p < 16; ++p) {
    Z += zpart[(size_t)p * NN + row];
    F += fpart[(size_t)p * NN + row];
  }
  float inv = 1.0f / Z;
  invZa[row] = inv;
  out[row] = F * inv + scal[0];
}

__global__ __launch_bounds__(256, 2) void k_sattn3(
    const unsigned char* __restrict__ qf8, const unsigned char* __restrict__ kf8,
    const float* __restrict__ invZa, float* __restrict__ S) {
  int rb = blockIdx.x >> 4;
  int cs = blockIdx.x & 15;
  int w = threadIdx.x >> 6;
  int lane = threadIdx.x & 63;
  int rA = lane & 15, kg = lane >> 4;
  int rowbase = rb * 256 + w * 64;
  int cbase = cs * 512;
  const float rs = 0.04419417382415922f;

  int32x8 a8[4][4];  // Q rows (B-operand after swap)
#pragma unroll
  for (int rt = 0; rt < 4; ++rt)
#pragma unroll
    for (int ki = 0; ki < 4; ++ki) {
      const uint4* p = (const uint4*)(qf8 + (size_t)(rowbase + rt * 16 + rA) * DA + ki * 128 + kg * 32);
      a8[rt][ki] = pack8(p[0], p[1]);
    }
  float iz[4];
#pragma unroll
  for (int rt = 0; rt < 4; ++rt)
    iz[rt] = invZa[rowbase + rt * 16 + rA];

  for (int ct = 0; ct < 32; ++ct) {
    int col0 = cbase + ct * 16;
    int32x8 b8[4];  // K cols (A-operand after swap)
#pragma unroll
    for (int ki = 0; ki < 4; ++ki) {
      const uint4* p = (const uint4*)(kf8 + (size_t)(col0 + rA) * DA + ki * 128 + kg * 32);
      b8[ki] = pack8(p[0], p[1]);
    }
#pragma unroll
    for (int rt = 0; rt < 4; ++rt) {
      f32x4 acc = {0.f, 0.f, 0.f, 0.f};
#pragma unroll
      for (int ki = 0; ki < 4; ++ki)
        acc = __builtin_amdgcn_mfma_scale_f32_16x16x128_f8f6f4(
            b8[ki], a8[rt][ki], acc, 0, 0, 0, 127, 0, 127);
      f32x4 ev;
      ev[0] = __expf(fminf(acc[0] * rs, 60.f)) * iz[rt];
      ev[1] = __expf(fminf(acc[1] * rs, 60.f)) * iz[rt];
      ev[2] = __expf(fminf(acc[2] * rs, 60.f)) * iz[rt];
      ev[3] = __expf(fminf(acc[3] * rs, 60.f)) * iz[rt];
      __builtin_nontemporal_store(
          ev, (f32x4*)&S[(size_t)(rowbase + rt * 16 + rA) * NN + col0 + kg * 4]);
    }
  }
}

extern "C" void kernel_launch(void* const* d_in, const int* in_sizes, int n_in,
                              void* d_out, int out_size, void* d_ws, size_t ws_size,
                              hipStream_t stream) {
  (void)in_sizes; (void)n_in; (void)out_size; (void)ws_size;
  const float* x    = (const float*)d_in[0];
  const int*   ei   = (const int*)d_in[1];
  const float* ea   = (const float*)d_in[2];
  const float* msw  = (const float*)d_in[3];
  const float* msb  = (const float*)d_in[4];
  const float* upw  = (const float*)d_in[5];
  const float* upb  = (const float*)d_in[6];
  const float* wihf = (const float*)d_in[7];
  const float* whhf = (const float*)d_in[8];
  const float* bihf = (const float*)d_in[9];
  const float* bhhf = (const float*)d_in[10];
  const float* wihr = (const float*)d_in[11];
  const float* whhr = (const float*)d_in[12];
  const float* bihr = (const float*)d_in[13];
  const float* bhhr = (const float*)d_in[14];
  const float* ipw  = (const float*)d_in[15];
  const float* ipb  = (const float*)d_in[16];
  const float* opw  = (const float*)d_in[17];
  const float* opb  = (const float*)d_in[18];
  const float* fcw  = (const float*)d_in[19];
  const float* fcb  = (const float*)d_in[20];
  float* out = (float*)d_out;

  char* ws = (char*)d_ws;
  size_t off = 0;
  auto alloc = [&](size_t bytes) {
    void* p = ws + off;
    off = (off + bytes + 255) & ~(size_t)255;
    return p;
  };
  float* aggr  = (float*)alloc((size_t)NN * DM * 4);
  _Float16* h16 = (_Float16*)alloc((size_t)NN * DN * 2);
  float* gf    = (float*)alloc((size_t)(NN + 1) * 1024 * 4);
  float* gr    = (float*)alloc((size_t)(NN + 1) * 1024 * 4);
  float* lstm  = (float*)alloc((size_t)NN * DA * 4);
  unsigned short* lstm_bf = (unsigned short*)alloc((size_t)NN * DA * 2);
  unsigned char* qf8      = (unsigned char*)alloc((size_t)NN * DA);
  unsigned char* kf8      = (unsigned char*)alloc((size_t)NN * DA);
  unsigned short* wbf     = (unsigned short*)alloc((size_t)1024 * DA * 2);
  _Float16* wpf = (_Float16*)alloc((size_t)1024 * HL * 2);
  _Float16* wpr = (_Float16*)alloc((size_t)1024 * HL * 2);
  _Float16* wif16 = (_Float16*)alloc((size_t)1024 * DN * 2);
  _Float16* wir16 = (_Float16*)alloc((size_t)1024 * DN * 2);
  unsigned int* deg    = (unsigned int*)alloc((size_t)NN * 4);
  unsigned int* rowptr = (unsigned int*)alloc((size_t)(NN + 1) * 4);
  unsigned int* cursor = (unsigned int*)alloc((size_t)NN * 4);
  int* eidx            = (int*)alloc((size_t)NE * 4);
  int* esrc            = (int*)alloc((size_t)NE * 4);
  float* wveff = (float*)alloc(DA * 4);
  float* veff  = (float*)alloc(NN * 4);
  float* invZa = (float*)alloc(NN * 4);
  float* zpart = (float*)alloc((size_t)16 * NN * 4);
  float* fpart = (float*)alloc((size_t)16 * NN * 4);
  float* scal  = (float*)alloc(64 * 4);

  hipMemsetAsync(deg, 0, (size_t)NN * 4, stream);

  k_csr_hist<<<NE / 256, 256, 0, stream>>>(ei, deg);
  k_csr_scan<<<1, 256, 0, stream>>>(deg, rowptr, cursor);
  k_csr_fill<<<NE / 256, 256, 0, stream>>>(ei, cursor, eidx, esrc);
  k_aggr<<<NN / 4, 256, 0, stream>>>(x, ea, eidx, esrc, rowptr, msw, msb, aggr);
  k_update<<<NN / 16, 128, 0, stream>>>(x, aggr, upw, upb, h16);
  k_prep<<<(1024 * HL + 1024 * DN + 1024 * DA) / 256, 256, 0, stream>>>(
      whhf, whhr, wihf, wihr, ipw, wpf, wpr, wif16, wir16, wbf);
  k_gates3<<<(NN / 16) * 8, 256, 0, stream>>>(h16, wif16, wir16, bihf, bhhf, bihr, bhhr, gf, gr);
  k_lstm5<<<256, 1024, 0, stream>>>(wpf, wpr, gf, gr, lstm, lstm_bf);
  k_eff<<<1, 512, 0, stream>>>(opw, fcw, fcb, opb, ipb, ipw, wveff, scal);
  k_veff<<<NN / 4, 256, 0, stream>>>(lstm, wveff, scal, veff);
  k_inproj<<<2048, 256, 0, stream>>>(lstm_bf, wbf, ipb, qf8, kf8);
  k_zsum3<<<512, 256, 0, stream>>>(qf8, kf8, veff, zpart, fpart);
  k_zred<<<NN / 256, 256, 0, stream>>>(zpart, fpart, scal, invZa, out);
  k_sattn3<<<512, 256, 0, stream>>>(qf8, kf8, invZa, out + NN);
}

// Round 16
// 639.683 us; speedup vs baseline: 1.0844x; 1.0844x over previous
//
#include <hip/hip_runtime.h>
#include <hip/hip_bf16.h>

#define NN 8192
#define NE 262144
#define DN 128
#define DE 10
#define DM 64
#define HL 256
#define DA 512

#define CS 64   // LSTM time-chunk size per WG
#define KW 24   // warm-up steps: worst chunk ~e^-13 ~ 2e-6 relative truncation

typedef __attribute__((ext_vector_type(2))) _Float16 h2_t;
typedef __attribute__((ext_vector_type(8))) short short8;
typedef __attribute__((ext_vector_type(4))) float f32x4;
typedef __attribute__((ext_vector_type(8))) int int32x8;
typedef __attribute__((ext_vector_type(8))) unsigned short ushort8;

__device__ __forceinline__ float fast_rcp(float x) {
#if __has_builtin(__builtin_amdgcn_rcpf)
  return __builtin_amdgcn_rcpf(x);
#else
  return 1.0f / x;
#endif
}
__device__ __forceinline__ float sigf(float x) {
  return fast_rcp(1.0f + __expf(-x));
}
__device__ __forceinline__ float tanh_fast(float x) {
  return 2.0f * fast_rcp(1.0f + __expf(-2.0f * x)) - 1.0f;
}
__device__ __forceinline__ float fdot2f(h2_t a, h2_t b, float c) {
#if __has_builtin(__builtin_amdgcn_fdot2)
  return __builtin_amdgcn_fdot2(a, b, c, false);
#else
  return c + (float)a.x * (float)b.x + (float)a.y * (float)b.y;
#endif
}
__device__ __forceinline__ h2_t bch2(unsigned int u) {
  return __builtin_bit_cast(h2_t, u);
}
__device__ __forceinline__ unsigned short f2bf(float v) {
  return __builtin_bit_cast(unsigned short, __float2bfloat16(v));
}
__device__ __forceinline__ float bf2f(unsigned short u) {
  return __builtin_bit_cast(float, (unsigned int)u << 16);
}

// Manual f32 -> OCP e4m3fn with RNE.
__device__ __forceinline__ unsigned char f2e4m3(float f) {
  unsigned int u = __builtin_bit_cast(unsigned int, f);
  unsigned int sign = (u >> 24) & 0x80u;
  unsigned int au = u & 0x7FFFFFFFu;
  float a = __builtin_bit_cast(float, au);
  if (a >= 464.0f) return (unsigned char)(sign | 0x7Eu);
  int e = (int)((au >> 23) & 0xFFu) - 127;
  if (e >= -6) {
    unsigned int man = au & 0x7FFFFFu;
    unsigned int m = man >> 20;
    unsigned int rest = man & 0xFFFFFu;
    m += (rest > 0x80000u) || ((rest == 0x80000u) && (m & 1u));
    unsigned int ee = (unsigned)(e + 7);
    if (m >= 8u) { m -= 8u; ee += 1u; }
    if (ee > 15u || (ee == 15u && m > 6u)) return (unsigned char)(sign | 0x7Eu);
    return (unsigned char)(sign | (ee << 3) | m);
  }
  int q = (int)rintf(a * 512.0f);
  if (q >= 8) return (unsigned char)(sign | 0x08u);
  return (unsigned char)(sign | (unsigned)q);
}

__device__ __forceinline__ int32x8 pack8(uint4 a, uint4 b) {
  int32x8 r;
  r[0] = (int)a.x; r[1] = (int)a.y; r[2] = (int)a.z; r[3] = (int)a.w;
  r[4] = (int)b.x; r[5] = (int)b.y; r[6] = (int)b.z; r[7] = (int)b.w;
  return r;
}

// ---------------- CSR build ----------------
__global__ void k_csr_hist(const int* __restrict__ ei, unsigned int* __restrict__ deg) {
  int e = blockIdx.x * 256 + threadIdx.x;
  if (e < NE) atomicAdd(&deg[ei[NE + e]], 1u);
}

__global__ __launch_bounds__(256) void k_csr_scan(
    const unsigned int* __restrict__ deg, unsigned int* __restrict__ rowptr,
    unsigned int* __restrict__ cursor) {
  __shared__ unsigned int tot[256];
  int t = threadIdx.x;
  unsigned int local[32];
  unsigned int s = 0;
  for (int i = 0; i < 32; ++i) {
    local[i] = s;
    s += deg[t * 32 + i];
  }
  tot[t] = s;
  __syncthreads();
  for (int d = 1; d < 256; d <<= 1) {
    unsigned int v = (t >= d) ? tot[t - d] : 0u;
    __syncthreads();
    tot[t] += v;
    __syncthreads();
  }
  unsigned int base = (t == 0) ? 0u : tot[t - 1];
  for (int i = 0; i < 32; ++i) {
    unsigned int r = base + local[i];
    rowptr[t * 32 + i] = r;
    cursor[t * 32 + i] = r;
  }
  if (t == 255) rowptr[NN] = tot[255];
}

// Fill stores BOTH the edge id (for ea) and the source node.
__global__ void k_csr_fill(const int* __restrict__ ei, unsigned int* __restrict__ cursor,
                           int* __restrict__ eidx, int* __restrict__ esrc) {
  int e = blockIdx.x * 256 + threadIdx.x;
  if (e < NE) {
    int d = ei[NE + e];
    unsigned int p = atomicAdd(&cursor[d], 1u);
    eidx[p] = e;
    esrc[p] = ei[e];
  }
}

// Gather-aggregate: aggr[n] = W @ (sum_e concat(x[src],ea)) + deg*b.
__global__ __launch_bounds__(256) void k_aggr(
    const float* __restrict__ x, const float* __restrict__ ea,
    const int* __restrict__ eidx, const int* __restrict__ esrc,
    const unsigned int* __restrict__ rowptr, const float* __restrict__ mw,
    const float* __restrict__ mb, float* __restrict__ aggr) {
  __shared__ float wT[DN + DE][DM];
  __shared__ float feat[4][DN + DE + 2];
  for (int i = threadIdx.x; i < (DN + DE) * DM; i += 256) {
    int k = i >> 6, o = i & 63;
    wT[k][o] = mw[o * (DN + DE) + k];
  }
  __syncthreads();
  int wv = threadIdx.x >> 6;
  int l = threadIdx.x & 63;
  int n = blockIdx.x * 4 + wv;
  unsigned int e0 = rowptr[n], e1 = rowptr[n + 1];
  float s0 = 0.f, s1 = 0.f, se = 0.f;
  for (unsigned int i = e0; i < e1; ++i) {
    int src = esrc[i];
    int e = eidx[i];
    const float* xr = x + (size_t)src * DN;
    s0 += xr[l];
    s1 += xr[64 + l];
    if (l < DE) se += ea[(size_t)e * DE + l];
  }
  feat[wv][l] = s0;
  feat[wv][64 + l] = s1;
  if (l < DE) feat[wv][128 + l] = se;
  __syncthreads();
  float degc = (float)(e1 - e0);
  float acc = mb[l] * degc;
#pragma unroll 2
  for (int k = 0; k < DN + DE; ++k) acc += feat[wv][k] * wT[k][l];
  aggr[(size_t)n * DM + l] = acc;
}

// Node update; emits h directly as f16 (sole consumer is the f16 gate MFMA).
__global__ void k_update(const float* __restrict__ x, const float* __restrict__ aggr,
                         const float* __restrict__ uw, const float* __restrict__ ub,
                         _Float16* __restrict__ h16) {
  __shared__ float l[16][DN + DM];
  int r0 = blockIdx.x * 16;
  for (int i = threadIdx.x; i < 16 * (DN + DM); i += 128) {
    int r = i / (DN + DM), k = i % (DN + DM);
    l[r][k] = (k < DN) ? x[(size_t)(r0 + r) * DN + k]
                       : aggr[(size_t)(r0 + r) * DM + (k - DN)];
  }
  __syncthreads();
  int o = threadIdx.x;
  float b = ub[o];
  float acc[16];
#pragma unroll
  for (int r = 0; r < 16; ++r) acc[r] = b;
  const float* wr = uw + (size_t)o * (DN + DM);
  for (int k = 0; k < DN + DM; ++k) {
    float wv = wr[k];
#pragma unroll
    for (int r = 0; r < 16; ++r) acc[r] += wv * l[r][k];
  }
#pragma unroll
  for (int r = 0; r < 16; ++r) h16[(size_t)(r0 + r) * DN + o] = (_Float16)acc[r];
}

// Gate GEMM v3: f16 MFMA, k_inproj pattern.
__global__ __launch_bounds__(256) void k_gates3(
    const _Float16* __restrict__ h16,
    const _Float16* __restrict__ wif16, const _Float16* __restrict__ wir16,
    const float* __restrict__ bif, const float* __restrict__ bhf,
    const float* __restrict__ bir, const float* __restrict__ bhr,
    float* __restrict__ gf, float* __restrict__ gr) {
  int rt = blockIdx.x >> 3;
  int cg = blockIdx.x & 7;
  int w = threadIdx.x >> 6;
  int lane = threadIdx.x & 63;
  int r0 = rt * 16;
  int rA = lane & 15;
  int kg = lane >> 4;
  int rev = cg >> 2;
  int colbase = (cg & 3) * 256 + w * 64;
  const _Float16* wb = rev ? wir16 : wif16;
  const float* b1 = rev ? bir : bif;
  const float* b2 = rev ? bhr : bhf;

  short8 a[4];
#pragma unroll
  for (int kk = 0; kk < 4; ++kk)
    a[kk] = *(const short8*)(h16 + (size_t)(r0 + rA) * DN + kk * 32 + kg * 8);

  for (int ct = 0; ct < 4; ++ct) {
    int col0 = colbase + ct * 16;
    f32x4 acc = {0.f, 0.f, 0.f, 0.f};
#pragma unroll
    for (int kk = 0; kk < 4; ++kk) {
      short8 b = *(const short8*)(wb + (size_t)(col0 + rA) * DN + kk * 32 + kg * 8);
      acc = __builtin_amdgcn_mfma_f32_16x16x32_f16(a[kk], b, acc, 0, 0, 0);
    }
    int col = col0 + rA;
    float bsum = b1[col] + b2[col];
#pragma unroll
    for (int i = 0; i < 4; ++i) {
      int row = r0 + kg * 4 + i;
      float v = acc[i] + bsum;
      if (!rev) gf[(size_t)row * 1024 + col] = v;
      else      gr[(size_t)(NN - 1 - row) * 1024 + col] = v;
    }
  }
}

// Fused weight conversions: w_hh (f,r) -> f16, w_ih (f,r) -> f16, ipw[q,k] -> bf16.
__global__ void k_prep(const float* __restrict__ whhf, const float* __restrict__ whhr,
                       const float* __restrict__ wihf, const float* __restrict__ wihr,
                       const float* __restrict__ ipw,
                       _Float16* __restrict__ wpf, _Float16* __restrict__ wpr,
                       _Float16* __restrict__ wif16, _Float16* __restrict__ wir16,
                       unsigned short* __restrict__ wbf) {
  int i = blockIdx.x * 256 + threadIdx.x;
  if (i < 1024 * HL) {
    wpf[i] = (_Float16)whhf[i];
    wpr[i] = (_Float16)whhr[i];
  } else if (i < 1024 * HL + 1024 * DN) {
    int j = i - 1024 * HL;
    wif16[j] = (_Float16)wihf[j];
    wir16[j] = (_Float16)wihr[j];
  } else {
    int j = i - (1024 * HL + 1024 * DN);
    wbf[j] = f2bf(ipw[j]);
  }
}

// Fused epilogue-algebra prep: effw (LDS), then wveff + scal[0,1].
__global__ __launch_bounds__(512) void k_eff(
    const float* __restrict__ opw, const float* __restrict__ fcw,
    const float* __restrict__ fcb, const float* __restrict__ opb,
    const float* __restrict__ ipb, const float* __restrict__ ipw,
    float* __restrict__ wveff, float* __restrict__ scal) {
  __shared__ float eff[512];
  __shared__ float red[512];
  int t = threadIdx.x;
  float s = 0.f;
  for (int d = 0; d < DA; ++d) s += fcw[d] * opw[(size_t)d * DA + t];
  eff[t] = s;
  __syncthreads();
  float wv = 0.f;
  for (int k = 0; k < DA; ++k) wv += eff[k] * ipw[(size_t)(2 * DA + k) * DA + t];
  wveff[t] = wv;
  red[t] = fcw[t] * opb[t];
  __syncthreads();
  for (int s2 = 256; s2 > 0; s2 >>= 1) {
    if (t < s2) red[t] += red[t + s2];
    __syncthreads();
  }
  if (t == 0) scal[0] = red[0] + fcb[0];
  __syncthreads();
  red[t] = ipb[2 * DA + t] * eff[t];
  __syncthreads();
  for (int s2 = 256; s2 > 0; s2 >>= 1) {
    if (t < s2) red[t] += red[t + s2];
    __syncthreads();
  }
  if (t == 0) scal[1] = red[0];
}

// Time-chunked BiLSTM v4 (proven fastest structure: 176us). 512 threads,
// K-split halves across waves; i/f/o in VGPRs, g in rotation-swizzled LDS;
// partial combine via LDS part[]; two barriers/step. Outputs bf16 only.
__global__ __launch_bounds__(512, 1) void k_lstm4(
    const _Float16* __restrict__ wp_f, const _Float16* __restrict__ wp_r,
    const float* __restrict__ gf, const float* __restrict__ gr,
    unsigned short* __restrict__ lstm_bf) {
  int dir = blockIdx.x & 1;
  int chunk = blockIdx.x >> 1;
  int tid = threadIdx.x;
  int kh = tid >> 8;
  int j = tid & 255;
  const _Float16* wp = dir ? wp_r : wp_f;
  const float* gates = dir ? gr : gf;

  __shared__ uint4 gw4[256 * 32];
  __shared__ unsigned int hsu[2][128];
  __shared__ float4 part[256];

  h2_t wi[64], wf2[64], wo[64];
  {
    const uint4* ri = (const uint4*)(wp + (size_t)j * HL + kh * 128);
    const uint4* rf = (const uint4*)(wp + (size_t)(256 + j) * HL + kh * 128);
    const uint4* ro = (const uint4*)(wp + (size_t)(768 + j) * HL + kh * 128);
#pragma unroll
    for (int s = 0; s < 16; ++s) {
      uint4 a = ri[s], b = rf[s], c = ro[s];
      wi[4 * s + 0] = bch2(a.x); wi[4 * s + 1] = bch2(a.y);
      wi[4 * s + 2] = bch2(a.z); wi[4 * s + 3] = bch2(a.w);
      wf2[4 * s + 0] = bch2(b.x); wf2[4 * s + 1] = bch2(b.y);
      wf2[4 * s + 2] = bch2(b.z); wf2[4 * s + 3] = bch2(b.w);
      wo[4 * s + 0] = bch2(c.x); wo[4 * s + 1] = bch2(c.y);
      wo[4 * s + 2] = bch2(c.z); wo[4 * s + 3] = bch2(c.w);
    }
  }
  {
    const uint4* rg = (const uint4*)(wp + (size_t)(512 + j) * HL + kh * 128);
#pragma unroll
    for (int s = 0; s < 16; ++s)
      gw4[j * 32 + ((kh * 16 + s + j) & 31)] = rg[s];
  }
  if (tid < 128) { hsu[0][tid] = 0u; hsu[1][tid] = 0u; }
  __syncthreads();

  int outstart = chunk * CS;
  int t0 = outstart - KW;
  if (t0 < 0) t0 = 0;
  int tend = outstart + CS;
  float c = 0.f;
  int cur = 0;
  int gswz = kh * 16 + j;

  for (int t = t0; t < tend; ++t) {
    float gi0 = 0.f, gff0 = 0.f, gg0 = 0.f, go0 = 0.f;
    if (kh == 0) {
      const float* gp = gates + (size_t)t * 1024 + j;
      gi0 = gp[0]; gff0 = gp[256]; gg0 = gp[512]; go0 = gp[768];
    }
    float di = 0.f, df = 0.f, dg = 0.f, do_ = 0.f;
    const uint4* hb = (const uint4*)&hsu[cur][kh * 64];
#pragma unroll
    for (int s = 0; s < 16; ++s) {
      uint4 hq = hb[s];
      uint4 gq = gw4[j * 32 + ((gswz + s) & 31)];
      di = fdot2f(wi[4 * s + 0], bch2(hq.x), di);
      di = fdot2f(wi[4 * s + 1], bch2(hq.y), di);
      di = fdot2f(wi[4 * s + 2], bch2(hq.z), di);
      di = fdot2f(wi[4 * s + 3], bch2(hq.w), di);
      df = fdot2f(wf2[4 * s + 0], bch2(hq.x), df);
      df = fdot2f(wf2[4 * s + 1], bch2(hq.y), df);
      df = fdot2f(wf2[4 * s + 2], bch2(hq.z), df);
      df = fdot2f(wf2[4 * s + 3], bch2(hq.w), df);
      dg = fdot2f(bch2(gq.x), bch2(hq.x), dg);
      dg = fdot2f(bch2(gq.y), bch2(hq.y), dg);
      dg = fdot2f(bch2(gq.z), bch2(hq.z), dg);
      dg = fdot2f(bch2(gq.w), bch2(hq.w), dg);
      do_ = fdot2f(wo[4 * s + 0], bch2(hq.x), do_);
      do_ = fdot2f(wo[4 * s + 1], bch2(hq.y), do_);
      do_ = fdot2f(wo[4 * s + 2], bch2(hq.z), do_);
      do_ = fdot2f(wo[4 * s + 3], bch2(hq.w), do_);
    }
    if (kh == 1) part[j] = (float4){di, df, dg, do_};
    __syncthreads();
    if (kh == 0) {
      float4 p = part[j];
      float i_ = sigf(gi0 + di + p.x);
      float f_ = sigf(gff0 + df + p.y);
      float g_ = tanh_fast(gg0 + dg + p.z);
      float o_ = sigf(go0 + do_ + p.w);
      c = f_ * c + i_ * g_;
      float hval = o_ * tanh_fast(c);
      if (t >= outstart) {
        size_t n = dir ? (size_t)(NN - 1 - t) : (size_t)t;
        lstm_bf[n * DA + dir * HL + j] = f2bf(hval);
      }
      ((_Float16*)hsu[cur ^ 1])[j] = (_Float16)hval;
    }
    __syncthreads();
    cur ^= 1;
  }
}

// veff[row] = dot(lstm_bf[row,:], wveff) + scal[1]  (bf16 inputs)
__global__ void k_veff(const unsigned short* __restrict__ lstm_bf,
                       const float* __restrict__ wveff,
                       const float* __restrict__ scal, float* __restrict__ veff) {
  int row = blockIdx.x * 4 + (threadIdx.x >> 6);
  int lane = threadIdx.x & 63;
  ushort8 v = *(const ushort8*)(lstm_bf + (size_t)row * DA + lane * 8);
  const float4* w = (const float4*)(wveff + lane * 8);
  float4 w0 = w[0], w1 = w[1];
  float s = bf2f(v[0]) * w0.x + bf2f(v[1]) * w0.y + bf2f(v[2]) * w0.z +
            bf2f(v[3]) * w0.w + bf2f(v[4]) * w1.x + bf2f(v[5]) * w1.y +
            bf2f(v[6]) * w1.z + bf2f(v[7]) * w1.w;
#pragma unroll
  for (int off = 1; off < 64; off <<= 1) s += __shfl_xor(s, off);
  if (lane == 0) veff[row] = s + scal[1];
}

// in_proj q,k via bf16 MFMA; outputs fp8 e4m3 (unscaled; 1/sqrt(512) applied
// post-MFMA in the attn passes).
__global__ void k_inproj(const unsigned short* __restrict__ lstm_bf,
                         const unsigned short* __restrict__ w_bf,
                         const float* __restrict__ ipb,
                         unsigned char* __restrict__ qf8,
                         unsigned char* __restrict__ kf8) {
  int rt = blockIdx.x >> 2;
  int cg = blockIdx.x & 3;
  int w = threadIdx.x >> 6;
  int lane = threadIdx.x & 63;
  int r0 = rt * 16;
  int rA = lane & 15;
  int kg = lane >> 4;
  short8 a[16];
#pragma unroll
  for (int kk = 0; kk < 16; ++kk)
    a[kk] = *(const short8*)(lstm_bf + (size_t)(r0 + rA) * DA + kk * 32 + kg * 8);
  for (int ct = 0; ct < 4; ++ct) {
    int col0 = cg * 256 + w * 64 + ct * 16;
    f32x4 acc = {0.f, 0.f, 0.f, 0.f};
#pragma unroll
    for (int kk = 0; kk < 16; ++kk) {
      short8 b = *(const short8*)(w_bf + (size_t)(col0 + rA) * DA + kk * 32 + kg * 8);
      acc = __builtin_amdgcn_mfma_f32_16x16x32_bf16(a[kk], b, acc, 0, 0, 0);
    }
    int col = col0 + rA;
    float bv = ipb[col];
#pragma unroll
    for (int i = 0; i < 4; ++i) {
      int rowo = r0 + kg * 4 + i;
      float v = acc[i] + bv;
      if (col < DA)
        qf8[(size_t)rowo * DA + col] = f2e4m3(v);
      else
        kf8[(size_t)rowo * DA + (col - DA)] = f2e4m3(v);
    }
  }
}

// ---- fp8 QK^T passes, operand-swapped (lane's 4 acc = 4 consecutive S-cols
// of one row): float4 stores, vectorized veff loads, 2-shfl reduction.

__global__ __launch_bounds__(256, 2) void k_zsum3(
    const unsigned char* __restrict__ qf8, const unsigned char* __restrict__ kf8,
    const float* __restrict__ veff,
    float* __restrict__ zpart, float* __restrict__ fpart) {
  int rb = blockIdx.x >> 4;
  int cs = blockIdx.x & 15;
  int w = threadIdx.x >> 6;
  int lane = threadIdx.x & 63;
  int rA = lane & 15, kg = lane >> 4;
  int rowbase = rb * 256 + w * 64;
  int cbase = cs * 512;
  const float rs = 0.04419417382415922f;

  int32x8 a8[4][4];  // Q rows (B-operand after swap)
#pragma unroll
  for (int rt = 0; rt < 4; ++rt)
#pragma unroll
    for (int ki = 0; ki < 4; ++ki) {
      const uint4* p = (const uint4*)(qf8 + (size_t)(rowbase + rt * 16 + rA) * DA + ki * 128 + kg * 32);
      a8[rt][ki] = pack8(p[0], p[1]);
    }
  float zs[4], fs[4];
#pragma unroll
  for (int rt = 0; rt < 4; ++rt) { zs[rt] = 0.f; fs[rt] = 0.f; }

  for (int ct = 0; ct < 32; ++ct) {
    int col0 = cbase + ct * 16;
    int32x8 b8[4];  // K cols (A-operand after swap)
#pragma unroll
    for (int ki = 0; ki < 4; ++ki) {
      const uint4* p = (const uint4*)(kf8 + (size_t)(col0 + rA) * DA + ki * 128 + kg * 32);
      b8[ki] = pack8(p[0], p[1]);
    }
    float4 vv4 = *(const float4*)&veff[col0 + kg * 4];
#pragma unroll
    for (int rt = 0; rt < 4; ++rt) {
      f32x4 acc = {0.f, 0.f, 0.f, 0.f};
#pragma unroll
      for (int ki = 0; ki < 4; ++ki)
        acc = __builtin_amdgcn_mfma_scale_f32_16x16x128_f8f6f4(
            b8[ki], a8[rt][ki], acc, 0, 0, 0, 127, 0, 127);
      float e0 = __expf(fminf(acc[0] * rs, 60.f));
      float e1 = __expf(fminf(acc[1] * rs, 60.f));
      float e2 = __expf(fminf(acc[2] * rs, 60.f));
      float e3 = __expf(fminf(acc[3] * rs, 60.f));
      zs[rt] += (e0 + e1) + (e2 + e3);
      fs[rt] += (e0 * vv4.x + e1 * vv4.y) + (e2 * vv4.z + e3 * vv4.w);
    }
  }
#pragma unroll
  for (int rt = 0; rt < 4; ++rt) {
    zs[rt] += __shfl_xor(zs[rt], 16);
    zs[rt] += __shfl_xor(zs[rt], 32);
    fs[rt] += __shfl_xor(fs[rt], 16);
    fs[rt] += __shfl_xor(fs[rt], 32);
  }
  if (lane < 16) {
#pragma unroll
    for (int rt = 0; rt < 4; ++rt) {
      int row = rowbase + rt * 16 + rA;
      zpart[(size_t)cs * NN + row] = zs[rt];
      fpart[(size_t)cs * NN + row] = fs[rt];
    }
  }
}

__global__ void k_zred(const float* __restrict__ zpart, const float* __restrict__ fpart,
                       const float* __restrict__ scal, float* __restrict__ invZa,
                       float* __restrict__ out) {
  int row = blockIdx.x * 256 + threadIdx.x;
  float Z = 0.f, F = 0.f;
#pragma unroll
  for (int p = 0; p < 16; ++p) {
    Z += zpart[(size_t)p * NN + row];
    F += fpart[(size_t)p * NN + row];
  }
  float inv = 1.0f / Z;
  invZa[row] = inv;
  out[row] = F * inv + scal[0];
}

__global__ __launch_bounds__(256, 2) void k_sattn3(
    const unsigned char* __restrict__ qf8, const unsigned char* __restrict__ kf8,
    const float* __restrict__ invZa, float* __restrict__ S) {
  int rb = blockIdx.x >> 4;
  int cs = blockIdx.x & 15;
  int w = threadIdx.x >> 6;
  int lane = threadIdx.x & 63;
  int rA = lane & 15, kg = lane >> 4;
  int rowbase = rb * 256 + w * 64;
  int cbase = cs * 512;
  const float rs = 0.04419417382415922f;

  int32x8 a8[4][4];  // Q rows (B-operand after swap)
#pragma unroll
  for (int rt = 0; rt < 4; ++rt)
#pragma unroll
    for (int ki = 0; ki < 4; ++ki) {
      const uint4* p = (const uint4*)(qf8 + (size_t)(rowbase + rt * 16 + rA) * DA + ki * 128 + kg * 32);
      a8[rt][ki] = pack8(p[0], p[1]);
    }
  float iz[4];
#pragma unroll
  for (int rt = 0; rt < 4; ++rt)
    iz[rt] = invZa[rowbase + rt * 16 + rA];

  for (int ct = 0; ct < 32; ++ct) {
    int col0 = cbase + ct * 16;
    int32x8 b8[4];  // K cols (A-operand after swap)
#pragma unroll
    for (int ki = 0; ki < 4; ++ki) {
      const uint4* p = (const uint4*)(kf8 + (size_t)(col0 + rA) * DA + ki * 128 + kg * 32);
      b8[ki] = pack8(p[0], p[1]);
    }
#pragma unroll
    for (int rt = 0; rt < 4; ++rt) {
      f32x4 acc = {0.f, 0.f, 0.f, 0.f};
#pragma unroll
      for (int ki = 0; ki < 4; ++ki)
        acc = __builtin_amdgcn_mfma_scale_f32_16x16x128_f8f6f4(
            b8[ki], a8[rt][ki], acc, 0, 0, 0, 127, 0, 127);
      f32x4 ev;
      ev[0] = __expf(fminf(acc[0] * rs, 60.f)) * iz[rt];
      ev[1] = __expf(fminf(acc[1] * rs, 60.f)) * iz[rt];
      ev[2] = __expf(fminf(acc[2] * rs, 60.f)) * iz[rt];
      ev[3] = __expf(fminf(acc[3] * rs, 60.f)) * iz[rt];
      __builtin_nontemporal_store(
          ev, (f32x4*)&S[(size_t)(rowbase + rt * 16 + rA) * NN + col0 + kg * 4]);
    }
  }
}

extern "C" void kernel_launch(void* const* d_in, const int* in_sizes, int n_in,
                              void* d_out, int out_size, void* d_ws, size_t ws_size,
                              hipStream_t stream) {
  (void)in_sizes; (void)n_in; (void)out_size; (void)ws_size;
  const float* x    = (const float*)d_in[0];
  const int*   ei   = (const int*)d_in[1];
  const float* ea   = (const float*)d_in[2];
  const float* msw  = (const float*)d_in[3];
  const float* msb  = (const float*)d_in[4];
  const float* upw  = (const float*)d_in[5];
  const float* upb  = (const float*)d_in[6];
  const float* wihf = (const float*)d_in[7];
  const float* whhf = (const float*)d_in[8];
  const float* bihf = (const float*)d_in[9];
  const float* bhhf = (const float*)d_in[10];
  const float* wihr = (const float*)d_in[11];
  const float* whhr = (const float*)d_in[12];
  const float* bihr = (const float*)d_in[13];
  const float* bhhr = (const float*)d_in[14];
  const float* ipw  = (const float*)d_in[15];
  const float* ipb  = (const float*)d_in[16];
  const float* opw  = (const float*)d_in[17];
  const float* opb  = (const float*)d_in[18];
  const float* fcw  = (const float*)d_in[19];
  const float* fcb  = (const float*)d_in[20];
  float* out = (float*)d_out;

  char* ws = (char*)d_ws;
  size_t off = 0;
  auto alloc = [&](size_t bytes) {
    void* p = ws + off;
    off = (off + bytes + 255) & ~(size_t)255;
    return p;
  };
  float* aggr  = (float*)alloc((size_t)NN * DM * 4);
  _Float16* h16 = (_Float16*)alloc((size_t)NN * DN * 2);
  float* gf    = (float*)alloc((size_t)(NN + 1) * 1024 * 4);
  float* gr    = (float*)alloc((size_t)(NN + 1) * 1024 * 4);
  unsigned short* lstm_bf = (unsigned short*)alloc((size_t)NN * DA * 2);
  unsigned char* qf8      = (unsigned char*)alloc((size_t)NN * DA);
  unsigned char* kf8      = (unsigned char*)alloc((size_t)NN * DA);
  unsigned short* wbf     = (unsigned short*)alloc((size_t)1024 * DA * 2);
  _Float16* wpf = (_Float16*)alloc((size_t)1024 * HL * 2);
  _Float16* wpr = (_Float16*)alloc((size_t)1024 * HL * 2);
  _Float16* wif16 = (_Float16*)alloc((size_t)1024 * DN * 2);
  _Float16* wir16 = (_Float16*)alloc((size_t)1024 * DN * 2);
  unsigned int* deg    = (unsigned int*)alloc((size_t)NN * 4);
  unsigned int* rowptr = (unsigned int*)alloc((size_t)(NN + 1) * 4);
  unsigned int* cursor = (unsigned int*)alloc((size_t)NN * 4);
  int* eidx            = (int*)alloc((size_t)NE * 4);
  int* esrc            = (int*)alloc((size_t)NE * 4);
  float* wveff = (float*)alloc(DA * 4);
  float* veff  = (float*)alloc(NN * 4);
  float* invZa = (float*)alloc(NN * 4);
  float* zpart = (float*)alloc((size_t)16 * NN * 4);
  float* fpart = (float*)alloc((size_t)16 * NN * 4);
  float* scal  = (float*)alloc(64 * 4);

  hipMemsetAsync(deg, 0, (size_t)NN * 4, stream);

  k_csr_hist<<<NE / 256, 256, 0, stream>>>(ei, deg);
  k_csr_scan<<<1, 256, 0, stream>>>(deg, rowptr, cursor);
  k_csr_fill<<<NE / 256, 256, 0, stream>>>(ei, cursor, eidx, esrc);
  k_aggr<<<NN / 4, 256, 0, stream>>>(x, ea, eidx, esrc, rowptr, msw, msb, aggr);
  k_update<<<NN / 16, 128, 0, stream>>>(x, aggr, upw, upb, h16);
  k_prep<<<(1024 * HL + 1024 * DN + 1024 * DA) / 256, 256, 0, stream>>>(
      whhf, whhr, wihf, wihr, ipw, wpf, wpr, wif16, wir16, wbf);
  k_gates3<<<(NN / 16) * 8, 256, 0, stream>>>(h16, wif16, wir16, bihf, bhhf, bihr, bhhr, gf, gr);
  k_lstm4<<<256, 512, 0, stream>>>(wpf, wpr, gf, gr, lstm_bf);
  k_eff<<<1, 512, 0, stream>>>(opw, fcw, fcb, opb, ipb, ipw, wveff, scal);
  k_veff<<<NN / 4, 256, 0, stream>>>(lstm_bf, wveff, scal, veff);
  k_inproj<<<2048, 256, 0, stream>>>(lstm_bf, wbf, ipb, qf8, kf8);
  k_zsum3<<<512, 256, 0, stream>>>(qf8, kf8, veff, zpart, fpart);
  k_zred<<<NN / 256, 256, 0, stream>>>(zpart, fpart, scal, invZa, out);
  k_sattn3<<<512, 256, 0, stream>>>(qf8, kf8, invZa, out + NN);
}